// Round 1
// baseline (4795.642 us; speedup 1.0000x reference)
//
#include <hip/hip_runtime.h>
#include <stdint.h>

#define HH_ 64
#define WW_ 64
#define NB 4
#define CIN 1024
#define CMID 512
#define NANCH (HH_*WW_*9)      // 36864
#define PRE_N 6000
#define POST_N 300
#define CAND_PAD 6144
#define NEGV (-1.0e10f)

// ---------------- workspace layout (float units) ----------------
#define X_OFF   0
#define X_SZ    (NB*CMID*HH_*WW_)        // 8,388,608
#define SC_OFF  (X_OFF + X_SZ)
#define SC_SZ   (NB*NANCH)               // 147,456
#define BX_OFF  (SC_OFF + SC_SZ)
#define BX_SZ   (NB*NANCH*4)             // 589,824
#define CSC_OFF (BX_OFF + BX_SZ)
#define CSC_SZ  (NB*CAND_PAD)
#define CBX_OFF (CSC_OFF + CSC_SZ)
#define CBX_SZ  (NB*CAND_PAD*4)
#define CIX_OFF (CBX_OFF + CBX_SZ)
#define CIX_SZ  (NB*CAND_PAD)

// =====================================================================
// Kernel 1: 3x3 conv (pad 1) + bias + ReLU as implicit GEMM.
// M=512 (co), N=16384 (b*4096 + h*64 + w), K=9216 (ci*9 + kh*3 + kw).
// 128x128 tile, BK=16, 256 threads, 8x8 per-thread, double-buffered LDS.
// =====================================================================
__global__ __launch_bounds__(256) void conv3_kernel(
    const float* __restrict__ in, const float* __restrict__ wgt,
    const float* __restrict__ bias, float* __restrict__ xout)
{
    constexpr int BM = 128, BN = 128, BK = 16;
    constexpr int NKIT = (CIN * 9) / BK;   // 576
    __shared__ float As[2][BK][BM + 4];
    __shared__ float Bs[2][BK][BN];

    const int tid = threadIdx.x;
    const int bn = blockIdx.x;   // 0..127
    const int bm = blockIdx.y;   // 0..3
    const int tx = tid & 15, ty = tid >> 4;

    // A-load mapping: float4 along k; rows a_r and a_r+64
    const int a_c4 = (tid & 3) << 2;      // 0,4,8,12
    const int a_r  = tid >> 2;            // 0..63
    const float* aptr = wgt + (size_t)(bm * BM + a_r) * 9216 + a_c4;

    // B-load mapping: 128 n-cols x 2 k-rows per pass, 8 passes
    const int b_n = tid & 127;
    const int b_k = tid >> 7;             // 0..1
    const int n   = bn * BN + b_n;
    const int bb  = n >> 12;
    const int hh  = (n >> 6) & 63;
    const int wp  = n & 63;
    const float* iptr = in + (size_t)bb * CIN * HH_ * WW_;

    float a0r[4], a1r[4], brg[8];
    float acc[8][8];
#pragma unroll
    for (int i = 0; i < 8; i++)
#pragma unroll
        for (int j = 0; j < 8; j++) acc[i][j] = 0.f;

    auto gload = [&](int k0) {
        float4 t0 = *(const float4*)(aptr + k0);
        float4 t1 = *(const float4*)(aptr + (size_t)64 * 9216 + k0);
        a0r[0] = t0.x; a0r[1] = t0.y; a0r[2] = t0.z; a0r[3] = t0.w;
        a1r[0] = t1.x; a1r[1] = t1.y; a1r[2] = t1.z; a1r[3] = t1.w;
#pragma unroll
        for (int p = 0; p < 8; p++) {
            int k  = k0 + 2 * p + b_k;
            int ci = k / 9;
            int r  = k - ci * 9;
            int kh = r / 3;
            int kw = r - kh * 3;
            int y  = hh + kh - 1;
            int x  = wp + kw - 1;
            float v = 0.f;
            if (((unsigned)y < 64u) && ((unsigned)x < 64u))
                v = iptr[(size_t)ci * 4096 + (y << 6) + x];
            brg[p] = v;
        }
    };
    auto sstore = [&](int buf) {
#pragma unroll
        for (int j = 0; j < 4; j++) {
            As[buf][a_c4 + j][a_r]      = a0r[j];
            As[buf][a_c4 + j][a_r + 64] = a1r[j];
        }
#pragma unroll
        for (int p = 0; p < 8; p++) Bs[buf][2 * p + b_k][b_n] = brg[p];
    };

    gload(0);
    sstore(0);
    __syncthreads();

    int buf = 0;
    for (int kt = 0; kt < NKIT; kt++) {
        if (kt + 1 < NKIT) gload((kt + 1) * BK);
#pragma unroll
        for (int kk = 0; kk < BK; kk++) {
            float a[8], b8[8];
            *(float4*)&a[0]  = *(const float4*)&As[buf][kk][ty * 8];
            *(float4*)&a[4]  = *(const float4*)&As[buf][kk][ty * 8 + 4];
            *(float4*)&b8[0] = *(const float4*)&Bs[buf][kk][tx * 8];
            *(float4*)&b8[4] = *(const float4*)&Bs[buf][kk][tx * 8 + 4];
#pragma unroll
            for (int i = 0; i < 8; i++)
#pragma unroll
                for (int j = 0; j < 8; j++)
                    acc[i][j] = fmaf(a[i], b8[j], acc[i][j]);
        }
        __syncthreads();
        if (kt + 1 < NKIT) sstore(buf ^ 1);
        __syncthreads();
        buf ^= 1;
    }

    // epilogue: bias + relu, store NCHW
    const int co0 = bm * BM + ty * 8;
    const int s0  = ((bn * BN) & 4095) + tx * 8;
    float* op = xout + ((size_t)bb * CMID + co0) * 4096 + s0;
#pragma unroll
    for (int i = 0; i < 8; i++) {
        float bv = bias[co0 + i];
        float r[8];
#pragma unroll
        for (int j = 0; j < 8; j++) r[j] = fmaxf(acc[i][j] + bv, 0.f);
        *(float4*)(op + (size_t)i * 4096)     = make_float4(r[0], r[1], r[2], r[3]);
        *(float4*)(op + (size_t)i * 4096 + 4) = make_float4(r[4], r[5], r[6], r[7]);
    }
}

// =====================================================================
// Kernel 2: 1x1 heads (cls 18 + bbox 36) + softmax + box decode + clip.
// One thread per spatial position; weights staged in LDS per 64-ci chunk.
// =====================================================================
__global__ __launch_bounds__(256) void heads_kernel(
    const float* __restrict__ X, const float* __restrict__ cls_w,
    const float* __restrict__ cls_b, const float* __restrict__ bbox_w,
    const float* __restrict__ bbox_b, const float* __restrict__ im_info,
    float* __restrict__ SC, float* __restrict__ BXo)
{
    __shared__ float Ws[54][64];
    const int tid = threadIdx.x;
    const int blk = blockIdx.x;            // 0..63
    const int b   = blk >> 4;              // 16 blocks per batch
    const int s   = ((blk & 15) << 8) + tid;  // 0..4095

    float acc[54];
#pragma unroll
    for (int j = 0; j < 18; j++) acc[j] = cls_b[j];
#pragma unroll
    for (int j = 0; j < 36; j++) acc[18 + j] = bbox_b[j];

    const float* xp = X + (size_t)b * CMID * 4096 + s;
    for (int c0 = 0; c0 < 512; c0 += 64) {
        __syncthreads();
        for (int e = tid; e < 54 * 64; e += 256) {
            int j = e >> 6, ci = e & 63;
            Ws[j][ci] = (j < 18) ? cls_w[j * 512 + c0 + ci]
                                 : bbox_w[(j - 18) * 512 + c0 + ci];
        }
        __syncthreads();
        for (int ci = 0; ci < 64; ci += 4) {
            float x0 = xp[(size_t)(c0 + ci) * 4096];
            float x1 = xp[(size_t)(c0 + ci + 1) * 4096];
            float x2 = xp[(size_t)(c0 + ci + 2) * 4096];
            float x3 = xp[(size_t)(c0 + ci + 3) * 4096];
#pragma unroll
            for (int j = 0; j < 54; j++) {
                float4 w4 = *(const float4*)&Ws[j][ci];
                acc[j] = fmaf(x3, w4.w, fmaf(x2, w4.z, fmaf(x1, w4.y, fmaf(x0, w4.x, acc[j]))));
            }
        }
    }

    const float imh = im_info[b * 3 + 0];
    const float imw = im_info[b * 3 + 1];
    const int hh = s >> 6, ww = s & 63;
    const float cxa = 7.5f + 16.f * (float)ww;
    const float cya = 7.5f + 16.f * (float)hh;
    const float WA[9] = {184.f, 368.f, 736.f, 128.f, 256.f, 512.f, 88.f, 176.f, 352.f};
    const float HA[9] = {96.f, 192.f, 384.f, 128.f, 256.f, 512.f, 176.f, 352.f, 704.f};
    const size_t base = (size_t)b * NANCH + (size_t)s * 9;
#pragma unroll
    for (int c = 0; c < 9; c++) {
        float bg = acc[c], fg = acc[9 + c];
        float m  = fmaxf(bg, fg);
        float e0 = expf(bg - m), e1 = expf(fg - m);
        float p  = e1 / (e0 + e1);
        float dx = acc[18 + 4 * c], dy = acc[19 + 4 * c];
        float dw = acc[20 + 4 * c], dh = acc[21 + 4 * c];
        float wa = WA[c], ha = HA[c];
        float cx = dx * wa + cxa;
        float cy = dy * ha + cya;
        float pw = expf(dw) * wa;
        float ph = expf(dh) * ha;
        float x1 = cx - 0.5f * pw, y1 = cy - 0.5f * ph;
        float x2 = cx + 0.5f * pw, y2 = cy + 0.5f * ph;
        x1 = fminf(fmaxf(x1, 0.f), imw - 1.f);
        y1 = fminf(fmaxf(y1, 0.f), imh - 1.f);
        x2 = fminf(fmaxf(x2, 0.f), imw - 1.f);
        y2 = fminf(fmaxf(y2, 0.f), imh - 1.f);
        SC[base + c] = p;
        *(float4*)&BXo[(base + c) * 4] = make_float4(x1, y1, x2, y2);
    }
}

// =====================================================================
// Kernel 3: per-batch exact top-6000 selection (set semantics).
// Binary search on float bit patterns (positive floats are order-
// isomorphic to uint bits). Ties at the cut value keep lowest indices
// (matches lax.top_k stability). Output order is irrelevant because the
// NMS argmax tie-breaks on original anchor index.
// =====================================================================
__global__ __launch_bounds__(1024) void select_kernel(
    const float* __restrict__ SC, const float* __restrict__ BX,
    float* __restrict__ CSC, float* __restrict__ CBX, int* __restrict__ CIX)
{
    const int b = blockIdx.x, tid = threadIdx.x;
    const float* sc = SC + (size_t)b * NANCH;
    const unsigned* bits = (const unsigned*)sc;
    __shared__ int s_cnt;
    __shared__ int s_c1, s_c2;
    __shared__ int s_tie[8192];

    unsigned lo = 0u, hi = 0x3f800001u;    // scores in (0, 1]
    while (hi - lo > 1u) {
        unsigned mid = lo + ((hi - lo) >> 1);
        if (tid == 0) s_cnt = 0;
        __syncthreads();
        int c = 0;
        for (int i = tid; i < NANCH; i += 1024) c += (bits[i] >= mid) ? 1 : 0;
#pragma unroll
        for (int off = 32; off; off >>= 1) c += __shfl_down(c, off);
        if ((tid & 63) == 0) atomicAdd(&s_cnt, c);
        __syncthreads();
        int total = s_cnt;
        __syncthreads();
        if (total >= PRE_N) lo = mid; else hi = mid;
    }
    const unsigned ustar = lo;

    // n1 = count(bits > ustar)  (strictly above the cut value)
    if (tid == 0) s_cnt = 0;
    __syncthreads();
    {
        int c = 0;
        for (int i = tid; i < NANCH; i += 1024) c += (bits[i] > ustar) ? 1 : 0;
#pragma unroll
        for (int off = 32; off; off >>= 1) c += __shfl_down(c, off);
        if ((tid & 63) == 0) atomicAdd(&s_cnt, c);
    }
    __syncthreads();
    const int n1 = s_cnt;
    __syncthreads();

    if (tid == 0) { s_c1 = 0; s_c2 = 0; }
    __syncthreads();

    const float4* bx4 = (const float4*)BX + (size_t)b * NANCH;
    float4* cbx4 = (float4*)CBX + (size_t)b * CAND_PAD;
    float*  csc  = CSC + (size_t)b * CAND_PAD;
    int*    cix  = CIX + (size_t)b * CAND_PAD;

    for (int i = tid; i < NANCH; i += 1024) {
        unsigned u = bits[i];
        if (u > ustar) {
            int p = atomicAdd(&s_c1, 1);
            csc[p] = sc[i]; cbx4[p] = bx4[i]; cix[p] = i;
        } else if (u == ustar) {
            int p = atomicAdd(&s_c2, 1);
            if (p < 8192) s_tie[p] = i;
        }
    }
    __syncthreads();
    int m = s_c2; if (m > 8192) m = 8192;
    const int need = PRE_N - n1;
    for (int i = tid; i < 8192; i += 1024)
        if (i >= m) s_tie[i] = 0x7fffffff;
    __syncthreads();

    // bitonic sort ascending (lowest anchor indices first)
    for (int k = 2; k <= 8192; k <<= 1) {
        for (int j = k >> 1; j > 0; j >>= 1) {
            for (int t = tid; t < 8192; t += 1024) {
                int ixj = t ^ j;
                if (ixj > t) {
                    int va = s_tie[t], vb = s_tie[ixj];
                    bool up = ((t & k) == 0);
                    if ((va > vb) == up) { s_tie[t] = vb; s_tie[ixj] = va; }
                }
            }
            __syncthreads();
        }
    }
    for (int t = tid; t < need; t += 1024) {
        int i = s_tie[t];
        int p = n1 + t;
        if (i >= 0 && i < NANCH) {
            csc[p] = sc[i]; cbx4[p] = bx4[i]; cix[p] = i;
        } else {   // pathological overflow fallback
            csc[p] = -2.0e10f; cix[p] = 0x7fffffff;
            cbx4[p] = make_float4(-4e9f, -4e9f, -4e9f, -4e9f);
        }
    }
    // sentinel pads 6000..6143
    for (int p = PRE_N + tid; p < CAND_PAD; p += 1024) {
        csc[p] = -2.0e10f;
        cix[p] = 0x7fffffff;
        cbx4[p] = make_float4(-4e9f, -4e9f, -4e9f, -4e9f);
    }
}

// =====================================================================
// Kernel 4: greedy NMS, one block per batch, all candidates in VGPRs
// (6 slots/thread x 1024 threads = 6144). 300 iterations of
// argmax (tie-break: min original index) -> broadcast -> IoU suppress.
// =====================================================================
__global__ __launch_bounds__(1024) void nms_kernel(
    const float* __restrict__ CSC, const float* __restrict__ CBX,
    const int* __restrict__ CIX, float* __restrict__ out)
{
    const int b = blockIdx.x, tid = threadIdx.x;
    const float*  csc = CSC + (size_t)b * CAND_PAD;
    const float4* cbx = (const float4*)CBX + (size_t)b * CAND_PAD;
    const int*    cix = CIX + (size_t)b * CAND_PAD;

    float sc[6], bx1[6], by1[6], bx2[6], by2[6], ar[6];
    int ix[6];
#pragma unroll
    for (int k = 0; k < 6; k++) {
        int g = tid + (k << 10);
        sc[k] = csc[g];
        float4 v = cbx[g];
        bx1[k] = v.x; by1[k] = v.y; bx2[k] = v.z; by2[k] = v.w;
        ar[k] = (v.z - v.x + 1.f) * (v.w - v.y + 1.f);
        ix[k] = cix[g];
    }

    __shared__ float ws_s[16];
    __shared__ int   ws_i[16];
    __shared__ float s_box[4];
    __shared__ float s_fs;
    __shared__ int   s_fi;

    float* rois = out + (size_t)b * 1500;
    float* oscr = out + 6000 + (size_t)b * 300;
    const int lane = tid & 63, wid = tid >> 6;

    for (int it = 0; it < POST_N; it++) {
        float bs = -3.0e38f; int bi = 0x7fffffff;
#pragma unroll
        for (int k = 0; k < 6; k++) {
            if (sc[k] > bs || (sc[k] == bs && ix[k] < bi)) { bs = sc[k]; bi = ix[k]; }
        }
#pragma unroll
        for (int off = 32; off; off >>= 1) {
            float os = __shfl_down(bs, off);
            int   oi = __shfl_down(bi, off);
            if (os > bs || (os == bs && oi < bi)) { bs = os; bi = oi; }
        }
        if (lane == 0) { ws_s[wid] = bs; ws_i[wid] = bi; }
        __syncthreads();
        if (tid < 64) {
            bs = (tid < 16) ? ws_s[tid] : -3.0e38f;
            bi = (tid < 16) ? ws_i[tid] : 0x7fffffff;
#pragma unroll
            for (int off = 8; off; off >>= 1) {
                float os = __shfl_down(bs, off);
                int   oi = __shfl_down(bi, off);
                if (os > bs || (os == bs && oi < bi)) { bs = os; bi = oi; }
            }
            if (tid == 0) { s_fs = bs; s_fi = bi; }
        }
        __syncthreads();
        const float ps = s_fs; const int pi = s_fi;
#pragma unroll
        for (int k = 0; k < 6; k++) {
            if (ix[k] == pi) {
                s_box[0] = bx1[k]; s_box[1] = by1[k];
                s_box[2] = bx2[k]; s_box[3] = by2[k];
            }
        }
        __syncthreads();
        const float px1 = s_box[0], py1 = s_box[1], px2 = s_box[2], py2 = s_box[3];
        const bool valid = ps > -5.0e9f;
        if (tid == 0) {
            float* r = rois + it * 5;
            r[0] = (float)b;
            r[1] = valid ? px1 : 0.f;
            r[2] = valid ? py1 : 0.f;
            r[3] = valid ? px2 : 0.f;
            r[4] = valid ? py2 : 0.f;
            oscr[it] = valid ? ps : 0.f;
        }
        const float parea = (px2 - px1 + 1.f) * (py2 - py1 + 1.f);
#pragma unroll
        for (int k = 0; k < 6; k++) {
            float xx1 = fmaxf(px1, bx1[k]);
            float yy1 = fmaxf(py1, by1[k]);
            float xx2 = fminf(px2, bx2[k]);
            float yy2 = fminf(py2, by2[k]);
            float iw = fmaxf(xx2 - xx1 + 1.f, 0.f);
            float ih = fmaxf(yy2 - yy1 + 1.f, 0.f);
            float inter = iw * ih;
            float iou = inter / (parea + ar[k] - inter);
            if (iou > 0.7f) sc[k] = NEGV;
        }
        // next iteration's first __syncthreads protects LDS reuse
    }
}

// =====================================================================
extern "C" void kernel_launch(void* const* d_in, const int* in_sizes, int n_in,
                              void* d_out, int out_size, void* d_ws, size_t ws_size,
                              hipStream_t stream)
{
    const float* base_feat = (const float*)d_in[0];
    const float* im_info   = (const float*)d_in[1];
    // d_in[2] gt_boxes, d_in[3] num_boxes: unused by reference
    const float* conv_w    = (const float*)d_in[4];
    const float* conv_b    = (const float*)d_in[5];
    const float* cls_w     = (const float*)d_in[6];
    const float* cls_b     = (const float*)d_in[7];
    const float* bbox_w    = (const float*)d_in[8];
    const float* bbox_b    = (const float*)d_in[9];

    float* ws  = (float*)d_ws;
    float* X   = ws + X_OFF;
    float* SC  = ws + SC_OFF;
    float* BX  = ws + BX_OFF;
    float* CSC = ws + CSC_OFF;
    float* CBX = ws + CBX_OFF;
    int*   CIX = (int*)(ws + CIX_OFF);
    float* out = (float*)d_out;

    hipLaunchKernelGGL(conv3_kernel, dim3(128, 4), dim3(256), 0, stream,
                       base_feat, conv_w, conv_b, X);
    hipLaunchKernelGGL(heads_kernel, dim3(64), dim3(256), 0, stream,
                       X, cls_w, cls_b, bbox_w, bbox_b, im_info, SC, BX);
    hipLaunchKernelGGL(select_kernel, dim3(4), dim3(1024), 0, stream,
                       SC, BX, CSC, CBX, CIX);
    hipLaunchKernelGGL(nms_kernel, dim3(4), dim3(1024), 0, stream,
                       CSC, CBX, CIX, out);
}

// Round 4
// 3726.423 us; speedup vs baseline: 1.2869x; 1.2869x over previous
//
#include <hip/hip_runtime.h>
#include <stdint.h>

#define HH_ 64
#define WW_ 64
#define NB 4
#define CIN 1024
#define CMID 512
#define NANCH (HH_*WW_*9)      // 36864
#define PRE_N 6000
#define POST_N 300
#define CAND_PAD 6144
#define NEGV (-1.0e10f)

// ---------------- workspace layout (float units) ----------------
#define X_OFF   0
#define X_SZ    (NB*CMID*HH_*WW_)        // 8,388,608
#define SC_OFF  (X_OFF + X_SZ)
#define SC_SZ   (NB*NANCH)               // 147,456
#define BX_OFF  (SC_OFF + SC_SZ)
#define BX_SZ   (NB*NANCH*4)             // 589,824
#define CSC_OFF (BX_OFF + BX_SZ)
#define CSC_SZ  (NB*CAND_PAD)
#define CBX_OFF (CSC_OFF + CSC_SZ)
#define CBX_SZ  (NB*CAND_PAD*4)
#define CIX_OFF (CBX_OFF + CBX_SZ)
#define CIX_SZ  (NB*CAND_PAD)
#define WT_OFF  (CIX_OFF + CIX_SZ)
#define WT_SZ   (9*512*1024)             // 4,718,592 (fp32 [r][co][ci])
// total ~14.3M floats = 57 MB

// =====================================================================
// Prep: weights fp32 [co][ci][3][3] -> fp32 [r][co][ci] (k-order r,ci).
// =====================================================================
__global__ __launch_bounds__(256) void prep_wt(
    const float* __restrict__ conv_w, float* __restrict__ WT)
{
    int o = blockIdx.x * 256 + threadIdx.x;      // < 4,718,592
    int ci = o & 1023, co = (o >> 10) & 511, r = o >> 19;
    WT[o] = conv_w[(size_t)(co * 1024 + ci) * 9 + r];
}

// =====================================================================
// Kernel 1: 3x3 conv (pad 1) + bias + ReLU, implicit GEMM, fp32 VALU.
// M=512 (co), N=16384 (b*4096+y*64+x), K = r*1024 + ci (r outer!).
// BM=128, BN=64, BK=16, 256 threads, thread tile 8m x 4n in two
// stride-4 strips ({t*4, 64+t*4}) -> 2-way LDS aliasing only (free).
// r is uniform within each BK chunk (1024/16=64 chunks per r) ->
// shift/validity are scalar; no div-9 in the hot path.
// =====================================================================
__global__ __launch_bounds__(256, 3) void conv3_fp32(
    const float* __restrict__ in, const float* __restrict__ WT,
    const float* __restrict__ bias, float* __restrict__ xout)
{
    constexpr int BK = 16;
    constexpr int NKIT = 576;            // 9216/16
    __shared__ float As[2][BK][132];     // [k][m], pad 132
    __shared__ float Bs[2][BK][64];      // [k][n]

    const int tid = threadIdx.x;
    const int bn = blockIdx.x;           // 0..255
    const int bm = blockIdx.y;           // 0..3
    const int tx = tid & 15, ty = tid >> 4;

    // ---- A staging map: row a_r (0..127), k-half (0..1) of 8 ----
    const int a_r  = tid >> 1;
    const int a_h8 = (tid & 1) << 3;     // 0 or 8
    const float* wtp = WT + (size_t)(bm * 128 + a_r) * 1024 + a_h8;

    // ---- B staging map: b_n (0..63), b_k4 (0..3) ----
    const int b_n = tid & 63;
    const int b_k4 = tid >> 6;
    const int n = bn * 64 + b_n;
    const int bb = n >> 12;              // BN=64 tiles never cross images
    const int sp = n & 4095;
    const int yy = (n >> 6) & 63, xx = n & 63;
    unsigned vmask = 0;
#pragma unroll
    for (int rr = 0; rr < 9; rr++) {
        int dy = rr / 3 - 1, dx = rr % 3 - 1;
        if ((unsigned)(yy + dy) < 64u && (unsigned)(xx + dx) < 64u)
            vmask |= 1u << rr;
    }
    const float* iptr = in + (size_t)bb * CIN * 4096;
    const int base_i = sp;               // + ci*4096 + shift per load

    float a0r[4], a1r[4], brg[4];
    float acc[8][4];
#pragma unroll
    for (int i = 0; i < 8; i++)
#pragma unroll
        for (int j = 0; j < 4; j++) acc[i][j] = 0.f;

    auto gload = [&](int kt) {
        const int r  = kt >> 6;
        const int cs = (kt & 63) << 4;
        const int kr = r / 3;
        const int shift = (kr - 1) * 64 + (r - 3 * kr - 1);
        const bool vb = (vmask >> r) & 1;
        // A: two float4 (k-contiguous in WT)
        const float* ap = wtp + (size_t)r * 524288 + cs;
        float4 t0 = *(const float4*)ap;
        float4 t1 = *(const float4*)(ap + 4);
        a0r[0]=t0.x; a0r[1]=t0.y; a0r[2]=t0.z; a0r[3]=t0.w;
        a1r[0]=t1.x; a1r[1]=t1.y; a1r[2]=t1.z; a1r[3]=t1.w;
        // B: 4 values, k-rows b_k4 + 4p
#pragma unroll
        for (int p = 0; p < 4; p++) {
            int ci = cs + b_k4 + 4 * p;
            int idx = base_i + (ci << 12) + shift;
            idx = vb ? idx : 0;
            float v = iptr[idx];
            brg[p] = vb ? v : 0.f;
        }
    };
    auto sstore = [&](int buf) {
#pragma unroll
        for (int q = 0; q < 4; q++) {
            As[buf][a_h8 + q][a_r]     = a0r[q];
            As[buf][a_h8 + 4 + q][a_r] = a1r[q];
        }
#pragma unroll
        for (int p = 0; p < 4; p++) Bs[buf][b_k4 + 4 * p][b_n] = brg[p];
    };

    gload(0);
    sstore(0);
    __syncthreads();

    int buf = 0;
    for (int kt = 0; kt < NKIT; kt++) {
        if (kt + 1 < NKIT) gload(kt + 1);
#pragma unroll
        for (int kk = 0; kk < BK; kk++) {
            float a[8], b4[4];
            *(float4*)&a[0] = *(const float4*)&As[buf][kk][ty * 4];
            *(float4*)&a[4] = *(const float4*)&As[buf][kk][64 + ty * 4];
            *(float4*)&b4[0] = *(const float4*)&Bs[buf][kk][tx * 4];
#pragma unroll
            for (int i = 0; i < 8; i++)
#pragma unroll
                for (int j = 0; j < 4; j++)
                    acc[i][j] = fmaf(a[i], b4[j], acc[i][j]);
        }
        __syncthreads();
        if (kt + 1 < NKIT) sstore(buf ^ 1);
        __syncthreads();
        buf ^= 1;
    }

    // epilogue: bias + relu, store NCHW (float4 per i)
    const int n0 = bn * 64 + tx * 4;
    const int spo = n0 & 4095;
#pragma unroll
    for (int i = 0; i < 8; i++) {
        int co = bm * 128 + ((i < 4) ? (ty * 4 + i) : (64 + ty * 4 + i - 4));
        float bv = bias[co];
        float4 rv;
        rv.x = fmaxf(acc[i][0] + bv, 0.f);
        rv.y = fmaxf(acc[i][1] + bv, 0.f);
        rv.z = fmaxf(acc[i][2] + bv, 0.f);
        rv.w = fmaxf(acc[i][3] + bv, 0.f);
        *(float4*)(xout + ((size_t)(bb * 512 + co)) * 4096 + spo) = rv;
    }
}

// =====================================================================
// Kernel 2: 1x1 heads + softmax + box decode + clip (exact R1 version).
// =====================================================================
__global__ __launch_bounds__(256) void heads_kernel(
    const float* __restrict__ X, const float* __restrict__ cls_w,
    const float* __restrict__ cls_b, const float* __restrict__ bbox_w,
    const float* __restrict__ bbox_b, const float* __restrict__ im_info,
    float* __restrict__ SC, float* __restrict__ BXo)
{
    __shared__ float Ws[54][64];
    const int tid = threadIdx.x;
    const int blk = blockIdx.x;            // 0..63
    const int b   = blk >> 4;
    const int s   = ((blk & 15) << 8) + tid;

    float acc[54];
#pragma unroll
    for (int j = 0; j < 18; j++) acc[j] = cls_b[j];
#pragma unroll
    for (int j = 0; j < 36; j++) acc[18 + j] = bbox_b[j];

    const float* xp = X + (size_t)b * CMID * 4096 + s;
    for (int c0 = 0; c0 < 512; c0 += 64) {
        __syncthreads();
        for (int e = tid; e < 54 * 64; e += 256) {
            int j = e >> 6, ci = e & 63;
            Ws[j][ci] = (j < 18) ? cls_w[j * 512 + c0 + ci]
                                 : bbox_w[(j - 18) * 512 + c0 + ci];
        }
        __syncthreads();
        for (int ci = 0; ci < 64; ci += 4) {
            float x0 = xp[(size_t)(c0 + ci) * 4096];
            float x1 = xp[(size_t)(c0 + ci + 1) * 4096];
            float x2 = xp[(size_t)(c0 + ci + 2) * 4096];
            float x3 = xp[(size_t)(c0 + ci + 3) * 4096];
#pragma unroll
            for (int j = 0; j < 54; j++) {
                float4 w4 = *(const float4*)&Ws[j][ci];
                acc[j] = fmaf(x3, w4.w, fmaf(x2, w4.z, fmaf(x1, w4.y, fmaf(x0, w4.x, acc[j]))));
            }
        }
    }

    const float imh = im_info[b * 3 + 0];
    const float imw = im_info[b * 3 + 1];
    const int hh = s >> 6, ww = s & 63;
    const float cxa = 7.5f + 16.f * (float)ww;
    const float cya = 7.5f + 16.f * (float)hh;
    const float WA[9] = {184.f, 368.f, 736.f, 128.f, 256.f, 512.f, 88.f, 176.f, 352.f};
    const float HA[9] = {96.f, 192.f, 384.f, 128.f, 256.f, 512.f, 176.f, 352.f, 704.f};
    const size_t base = (size_t)b * NANCH + (size_t)s * 9;
#pragma unroll
    for (int c = 0; c < 9; c++) {
        float bg = acc[c], fg = acc[9 + c];
        float m  = fmaxf(bg, fg);
        float e0 = expf(bg - m), e1 = expf(fg - m);
        float p  = e1 / (e0 + e1);
        float dx = acc[18 + 4 * c], dy = acc[19 + 4 * c];
        float dw = acc[20 + 4 * c], dh = acc[21 + 4 * c];
        float wa = WA[c], ha = HA[c];
        float cx = dx * wa + cxa;
        float cy = dy * ha + cya;
        float pw = expf(dw) * wa;
        float ph = expf(dh) * ha;
        float x1 = cx - 0.5f * pw, y1 = cy - 0.5f * ph;
        float x2 = cx + 0.5f * pw, y2 = cy + 0.5f * ph;
        x1 = fminf(fmaxf(x1, 0.f), imw - 1.f);
        y1 = fminf(fmaxf(y1, 0.f), imh - 1.f);
        x2 = fminf(fmaxf(x2, 0.f), imw - 1.f);
        y2 = fminf(fmaxf(y2, 0.f), imh - 1.f);
        SC[base + c] = p;
        *(float4*)&BXo[(base + c) * 4] = make_float4(x1, y1, x2, y2);
    }
}

// =====================================================================
// Kernel 3: per-batch exact top-6000 selection (exact R1 version).
// =====================================================================
__global__ __launch_bounds__(1024) void select_kernel(
    const float* __restrict__ SC, const float* __restrict__ BX,
    float* __restrict__ CSC, float* __restrict__ CBX, int* __restrict__ CIX)
{
    const int b = blockIdx.x, tid = threadIdx.x;
    const float* sc = SC + (size_t)b * NANCH;
    const unsigned* bits = (const unsigned*)sc;
    __shared__ int s_cnt;
    __shared__ int s_c1, s_c2;
    __shared__ int s_tie[8192];

    unsigned lo = 0u, hi = 0x3f800001u;
    while (hi - lo > 1u) {
        unsigned mid = lo + ((hi - lo) >> 1);
        if (tid == 0) s_cnt = 0;
        __syncthreads();
        int c = 0;
        for (int i = tid; i < NANCH; i += 1024) c += (bits[i] >= mid) ? 1 : 0;
#pragma unroll
        for (int off = 32; off; off >>= 1) c += __shfl_down(c, off);
        if ((tid & 63) == 0) atomicAdd(&s_cnt, c);
        __syncthreads();
        int total = s_cnt;
        __syncthreads();
        if (total >= PRE_N) lo = mid; else hi = mid;
    }
    const unsigned ustar = lo;

    if (tid == 0) s_cnt = 0;
    __syncthreads();
    {
        int c = 0;
        for (int i = tid; i < NANCH; i += 1024) c += (bits[i] > ustar) ? 1 : 0;
#pragma unroll
        for (int off = 32; off; off >>= 1) c += __shfl_down(c, off);
        if ((tid & 63) == 0) atomicAdd(&s_cnt, c);
    }
    __syncthreads();
    const int n1 = s_cnt;
    __syncthreads();

    if (tid == 0) { s_c1 = 0; s_c2 = 0; }
    __syncthreads();

    const float4* bx4 = (const float4*)BX + (size_t)b * NANCH;
    float4* cbx4 = (float4*)CBX + (size_t)b * CAND_PAD;
    float*  csc  = CSC + (size_t)b * CAND_PAD;
    int*    cix  = CIX + (size_t)b * CAND_PAD;

    for (int i = tid; i < NANCH; i += 1024) {
        unsigned u = bits[i];
        if (u > ustar) {
            int p = atomicAdd(&s_c1, 1);
            csc[p] = sc[i]; cbx4[p] = bx4[i]; cix[p] = i;
        } else if (u == ustar) {
            int p = atomicAdd(&s_c2, 1);
            if (p < 8192) s_tie[p] = i;
        }
    }
    __syncthreads();
    int m = s_c2; if (m > 8192) m = 8192;
    const int need = PRE_N - n1;
    for (int i = tid; i < 8192; i += 1024)
        if (i >= m) s_tie[i] = 0x7fffffff;
    __syncthreads();

    for (int k = 2; k <= 8192; k <<= 1) {
        for (int j = k >> 1; j > 0; j >>= 1) {
            for (int t = tid; t < 8192; t += 1024) {
                int ixj = t ^ j;
                if (ixj > t) {
                    int va = s_tie[t], vb = s_tie[ixj];
                    bool up = ((t & k) == 0);
                    if ((va > vb) == up) { s_tie[t] = vb; s_tie[ixj] = va; }
                }
            }
            __syncthreads();
        }
    }
    for (int t = tid; t < need; t += 1024) {
        int i = s_tie[t];
        int p = n1 + t;
        if (i >= 0 && i < NANCH) {
            csc[p] = sc[i]; cbx4[p] = bx4[i]; cix[p] = i;
        } else {
            csc[p] = -2.0e10f; cix[p] = 0x7fffffff;
            cbx4[p] = make_float4(-4e9f, -4e9f, -4e9f, -4e9f);
        }
    }
    for (int p = PRE_N + tid; p < CAND_PAD; p += 1024) {
        csc[p] = -2.0e10f;
        cix[p] = 0x7fffffff;
        cbx4[p] = make_float4(-4e9f, -4e9f, -4e9f, -4e9f);
    }
}

// =====================================================================
// Kernel 4: greedy NMS (exact R1 version).
// =====================================================================
__global__ __launch_bounds__(1024) void nms_kernel(
    const float* __restrict__ CSC, const float* __restrict__ CBX,
    const int* __restrict__ CIX, float* __restrict__ out)
{
    const int b = blockIdx.x, tid = threadIdx.x;
    const float*  csc = CSC + (size_t)b * CAND_PAD;
    const float4* cbx = (const float4*)CBX + (size_t)b * CAND_PAD;
    const int*    cix = CIX + (size_t)b * CAND_PAD;

    float sc[6], bx1[6], by1[6], bx2[6], by2[6], ar[6];
    int ix[6];
#pragma unroll
    for (int k = 0; k < 6; k++) {
        int g = tid + (k << 10);
        sc[k] = csc[g];
        float4 v = cbx[g];
        bx1[k] = v.x; by1[k] = v.y; bx2[k] = v.z; by2[k] = v.w;
        ar[k] = (v.z - v.x + 1.f) * (v.w - v.y + 1.f);
        ix[k] = cix[g];
    }

    __shared__ float ws_s[16];
    __shared__ int   ws_i[16];
    __shared__ float s_box[4];
    __shared__ float s_fs;
    __shared__ int   s_fi;

    float* rois = out + (size_t)b * 1500;
    float* oscr = out + 6000 + (size_t)b * 300;
    const int lane = tid & 63, wid = tid >> 6;

    for (int it = 0; it < POST_N; it++) {
        float bs = -3.0e38f; int bi = 0x7fffffff;
#pragma unroll
        for (int k = 0; k < 6; k++) {
            if (sc[k] > bs || (sc[k] == bs && ix[k] < bi)) { bs = sc[k]; bi = ix[k]; }
        }
#pragma unroll
        for (int off = 32; off; off >>= 1) {
            float os = __shfl_down(bs, off);
            int   oi = __shfl_down(bi, off);
            if (os > bs || (os == bs && oi < bi)) { bs = os; bi = oi; }
        }
        if (lane == 0) { ws_s[wid] = bs; ws_i[wid] = bi; }
        __syncthreads();
        if (tid < 64) {
            bs = (tid < 16) ? ws_s[tid] : -3.0e38f;
            bi = (tid < 16) ? ws_i[tid] : 0x7fffffff;
#pragma unroll
            for (int off = 8; off; off >>= 1) {
                float os = __shfl_down(bs, off);
                int   oi = __shfl_down(bi, off);
                if (os > bs || (os == bs && oi < bi)) { bs = os; bi = oi; }
            }
            if (tid == 0) { s_fs = bs; s_fi = bi; }
        }
        __syncthreads();
        const float ps = s_fs; const int pi = s_fi;
#pragma unroll
        for (int k = 0; k < 6; k++) {
            if (ix[k] == pi) {
                s_box[0] = bx1[k]; s_box[1] = by1[k];
                s_box[2] = bx2[k]; s_box[3] = by2[k];
            }
        }
        __syncthreads();
        const float px1 = s_box[0], py1 = s_box[1], px2 = s_box[2], py2 = s_box[3];
        const bool valid = ps > -5.0e9f;
        if (tid == 0) {
            float* r = rois + it * 5;
            r[0] = (float)b;
            r[1] = valid ? px1 : 0.f;
            r[2] = valid ? py1 : 0.f;
            r[3] = valid ? px2 : 0.f;
            r[4] = valid ? py2 : 0.f;
            oscr[it] = valid ? ps : 0.f;
        }
        const float parea = (px2 - px1 + 1.f) * (py2 - py1 + 1.f);
#pragma unroll
        for (int k = 0; k < 6; k++) {
            float xx1 = fmaxf(px1, bx1[k]);
            float yy1 = fmaxf(py1, by1[k]);
            float xx2 = fminf(px2, bx2[k]);
            float yy2 = fminf(py2, by2[k]);
            float iw = fmaxf(xx2 - xx1 + 1.f, 0.f);
            float ih = fmaxf(yy2 - yy1 + 1.f, 0.f);
            float inter = iw * ih;
            float iou = inter / (parea + ar[k] - inter);
            if (iou > 0.7f) sc[k] = NEGV;
        }
    }
}

// =====================================================================
extern "C" void kernel_launch(void* const* d_in, const int* in_sizes, int n_in,
                              void* d_out, int out_size, void* d_ws, size_t ws_size,
                              hipStream_t stream)
{
    const float* base_feat = (const float*)d_in[0];
    const float* im_info   = (const float*)d_in[1];
    const float* conv_w    = (const float*)d_in[4];
    const float* conv_b    = (const float*)d_in[5];
    const float* cls_w     = (const float*)d_in[6];
    const float* cls_b     = (const float*)d_in[7];
    const float* bbox_w    = (const float*)d_in[8];
    const float* bbox_b    = (const float*)d_in[9];

    float* ws  = (float*)d_ws;
    float* X   = ws + X_OFF;
    float* SC  = ws + SC_OFF;
    float* BX  = ws + BX_OFF;
    float* CSC = ws + CSC_OFF;
    float* CBX = ws + CBX_OFF;
    int*   CIX = (int*)(ws + CIX_OFF);
    float* WT  = ws + WT_OFF;
    float* out = (float*)d_out;

    hipLaunchKernelGGL(prep_wt, dim3(18432), dim3(256), 0, stream,
                       conv_w, WT);
    hipLaunchKernelGGL(conv3_fp32, dim3(256, 4), dim3(256), 0, stream,
                       base_feat, WT, conv_b, X);
    hipLaunchKernelGGL(heads_kernel, dim3(64), dim3(256), 0, stream,
                       X, cls_w, cls_b, bbox_w, bbox_b, im_info, SC, BX);
    hipLaunchKernelGGL(select_kernel, dim3(4), dim3(1024), 0, stream,
                       SC, BX, CSC, CBX, CIX);
    hipLaunchKernelGGL(nms_kernel, dim3(4), dim3(1024), 0, stream,
                       CSC, CBX, CIX, out);
}